// Round 5
// baseline (1041.616 us; speedup 1.0000x reference)
//
#include <hip/hip_runtime.h>
#include <hip/hip_bf16.h>

typedef __attribute__((ext_vector_type(8))) short bf16x8;
typedef __attribute__((ext_vector_type(4))) float f32x4;

// ---------- helpers ----------
__device__ __forceinline__ float b2f(unsigned int u) {
  union { unsigned int i; float f; } v; v.i = u << 16; return v.f;
}
__device__ __forceinline__ unsigned short f2b(float f) {
  unsigned int x = __float_as_uint(f);
  unsigned int r = (x + 0x7fffu + ((x >> 16) & 1u)) >> 16;  // RNE
  return (unsigned short)r;
}
__device__ __forceinline__ float mish_f(float x) {
  float sp = (x > 20.f) ? x : log1pf(expf(x));
  return x * tanhf(sp);
}

// ---------- dtype detector: flags[0]=inputs are f32, flags[1]=indexes are i64 ----------
__global__ __launch_bounds__(256) void detect_flags(
    const unsigned short* __restrict__ trees_u16,
    const unsigned int* __restrict__ idx_u32, int* __restrict__ flags)
{
  __shared__ int cnt_sane, cnt_nz;
  const int tid = threadIdx.x;
  if (tid == 0) { cnt_sane = 0; cnt_nz = 0; }
  __syncthreads();
  int sane = 0;
  for (int i = tid; i < 2048; i += 256) {
    unsigned short w = trees_u16[i];
    unsigned int e = (w >> 7) & 0xFFu;
    if ((w & 0x7FFFu) == 0 || (e >= 117u && e <= 133u)) sane++;
  }
  atomicAdd(&cnt_sane, sane);
  int nz = 0;
  for (int i = tid; i < 4096; i += 256) {
    if (idx_u32[2 * i + 1] != 0u) nz++;
  }
  atomicAdd(&cnt_nz, nz);
  __syncthreads();
  if (tid == 0) {
    flags[0] = (cnt_sane < 1843) ? 1 : 0;
    flags[1] = (cnt_nz == 0) ? 1 : 0;
  }
}

// ---------- K1: x = mish(bn(trees @ W_lin^T + b_lin)) -> (256,16,256) bf16 ----------
__global__ __launch_bounds__(256) void linear_bn_mish(
    const void* __restrict__ treesv, const void* __restrict__ Wlv,
    const void* __restrict__ blv, const void* __restrict__ gamv,
    const void* __restrict__ betv, const void* __restrict__ muv,
    const void* __restrict__ varv, unsigned short* __restrict__ out,
    const int* __restrict__ flags)
{
  __shared__ float As[16][64];
  __shared__ float Bs[16][64];
  const int F = flags[0];
  const int tid = threadIdx.x;
  const int tx = tid & 15, ty = tid >> 4;
  const int j0 = blockIdx.x * 64, b0 = blockIdx.y * 64;
  const int lr = tid >> 2, lc = (tid & 3) << 2;
  const unsigned short* t16 = (const unsigned short*)treesv;
  const float* t32 = (const float*)treesv;
  const unsigned short* w16 = (const unsigned short*)Wlv;
  const float* w32 = (const float*)Wlv;
  float acc[4][4] = {};
  for (int k0 = 0; k0 < 512; k0 += 16) {
    float a0, a1, a2, a3, q0, q1, q2, q3;
    if (F) {
      float4 ta = *(const float4*)(t32 + (b0 + lr) * 512 + k0 + lc);
      float4 tb = *(const float4*)(w32 + (j0 + lr) * 512 + k0 + lc);
      a0 = ta.x; a1 = ta.y; a2 = ta.z; a3 = ta.w;
      q0 = tb.x; q1 = tb.y; q2 = tb.z; q3 = tb.w;
    } else {
      ushort4 ta = *(const ushort4*)(t16 + (b0 + lr) * 512 + k0 + lc);
      ushort4 tb = *(const ushort4*)(w16 + (j0 + lr) * 512 + k0 + lc);
      a0 = b2f(ta.x); a1 = b2f(ta.y); a2 = b2f(ta.z); a3 = b2f(ta.w);
      q0 = b2f(tb.x); q1 = b2f(tb.y); q2 = b2f(tb.z); q3 = b2f(tb.w);
    }
    __syncthreads();
    As[lc + 0][lr] = a0; As[lc + 1][lr] = a1; As[lc + 2][lr] = a2; As[lc + 3][lr] = a3;
    Bs[lc + 0][lr] = q0; Bs[lc + 1][lr] = q1; Bs[lc + 2][lr] = q2; Bs[lc + 3][lr] = q3;
    __syncthreads();
#pragma unroll
    for (int kk = 0; kk < 16; ++kk) {
      float4 av = *(const float4*)&As[kk][ty * 4];
      float4 bv = *(const float4*)&Bs[kk][tx * 4];
      float a[4] = {av.x, av.y, av.z, av.w};
      float bb[4] = {bv.x, bv.y, bv.z, bv.w};
#pragma unroll
      for (int iy = 0; iy < 4; ++iy)
#pragma unroll
        for (int jx = 0; jx < 4; ++jx) acc[iy][jx] += a[iy] * bb[jx];
    }
  }
  const unsigned short* bl16 = (const unsigned short*)blv;  const float* bl32 = (const float*)blv;
  const unsigned short* g16 = (const unsigned short*)gamv;  const float* g32 = (const float*)gamv;
  const unsigned short* be16 = (const unsigned short*)betv; const float* be32 = (const float*)betv;
  const unsigned short* m16 = (const unsigned short*)muv;   const float* m32 = (const float*)muv;
  const unsigned short* v16 = (const unsigned short*)varv;  const float* v32 = (const float*)varv;
#pragma unroll
  for (int iy = 0; iy < 4; ++iy) {
    int b = b0 + ty * 4 + iy;
    unsigned short st[4];
#pragma unroll
    for (int jx = 0; jx < 4; ++jx) {
      int j = j0 + tx * 4 + jx;
      float bj = F ? bl32[j] : b2f(bl16[j]);
      float gj = F ? g32[j] : b2f(g16[j]);
      float ej = F ? be32[j] : b2f(be16[j]);
      float mj = F ? m32[j] : b2f(m16[j]);
      float vj = F ? v32[j] : b2f(v16[j]);
      float v = acc[iy][jx] + bj;
      v = (v - mj) * rsqrtf(vj + 1e-5f) * gj + ej;
      v = mish_f(v);
      st[jx] = f2b(v);
    }
    ushort4 pack; pack.x = st[0]; pack.y = st[1]; pack.z = st[2]; pack.w = st[3];
    *(ushort4*)(out + b * 4096 + j0 + tx * 4) = pack;
  }
}

// ---------- VALU tree conv (small layers 0,1): x [b][c][n] -> raw [b][o][n] ----------
template<int CIN, int COUT, int TO>
__global__ __launch_bounds__(256) void tree_conv(
    const unsigned short* __restrict__ xin,
    const void* __restrict__ idxv,
    const void* __restrict__ wv,
    const void* __restrict__ biasv,
    unsigned short* __restrict__ out,
    const int* __restrict__ flags)
{
  constexpr int CC = 16;
  constexpr int KC = CC * 3;
  constexpr int UO = TO / 16;
  constexpr int PE = (TO * KC) / 256;
  __shared__ float xs[CC][256];
  __shared__ float wsm[KC][TO];
  const int F = flags[0], G = flags[1];
  const int tid = threadIdx.x;
  const int tx = tid & 15, ty = tid >> 4;
  const int b = blockIdx.z;
  const int o0 = blockIdx.y * TO;
  const int n0 = blockIdx.x * 64;
  const unsigned short* xb = xin + b * CIN * 256;
  const unsigned short* wt16 = (const unsigned short*)wv;
  const float* wt32 = (const float*)wv;
  const int* idx32 = (const int*)idxv;

  int jj[4][3];
  int np[4];
  {
    const int step = G ? 2 : 1;
    const int* idxb = idx32 + b * 765 * step;
#pragma unroll
    for (int ni = 0; ni < 4; ++ni) {
      int n = n0 + tx * 4 + ni;
      np[ni] = n;
      int m = n - 1;
#pragma unroll
      for (int k = 0; k < 3; ++k) jj[ni][k] = (m >= 0) ? idxb[(3 * m + k) * step] : 0;
    }
  }

  float acc[UO][4];
#pragma unroll
  for (int u = 0; u < UO; ++u)
#pragma unroll
    for (int ni = 0; ni < 4; ++ni) acc[u][ni] = 0.f;

  for (int c0 = 0; c0 < CIN; c0 += CC) {
    __syncthreads();
    {
      const uint4* src = (const uint4*)(xb + c0 * 256);
      uint4 v0 = src[tid * 2];
      uint4 v1 = src[tid * 2 + 1];
      unsigned int ww[8] = {v0.x, v0.y, v0.z, v0.w, v1.x, v1.y, v1.z, v1.w};
      float t[16];
#pragma unroll
      for (int q = 0; q < 8; ++q) {
        t[2 * q] = b2f(ww[q] & 0xffffu);
        t[2 * q + 1] = b2f(ww[q] >> 16);
      }
      float* dst = &xs[tid >> 4][(tid & 15) * 16];
#pragma unroll
      for (int q = 0; q < 4; ++q)
        *(float4*)(dst + 4 * q) = make_float4(t[4 * q], t[4 * q + 1], t[4 * q + 2], t[4 * q + 3]);
    }
    if (F) {
#pragma unroll
      for (int e = 0; e < PE; ++e) {
        int p = e * 256 + tid;
        int o_rel = p / KC;
        int rem = p - o_rel * KC;
        wsm[rem][o_rel] = wt32[(o0 + o_rel) * CIN * 3 + c0 * 3 + rem];
      }
    } else {
#pragma unroll
      for (int e = 0; e < PE; ++e) {
        int p = e * 256 + tid;
        int o_rel = p / KC;
        int rem = p - o_rel * KC;
        wsm[rem][o_rel] = b2f(wt16[(o0 + o_rel) * CIN * 3 + c0 * 3 + rem]);
      }
    }
    __syncthreads();
#pragma unroll
    for (int cc = 0; cc < CC; ++cc) {
      float wvv[3][UO];
#pragma unroll
      for (int k = 0; k < 3; ++k) {
        if constexpr (UO == 4) {
          float4 f = *(const float4*)&wsm[cc * 3 + k][ty * 4];
          wvv[k][0] = f.x; wvv[k][1] = f.y; wvv[k][2] = f.z; wvv[k][3] = f.w;
        } else {
          float2 f = *(const float2*)&wsm[cc * 3 + k][ty * 2];
          wvv[k][0] = f.x; wvv[k][1] = f.y;
        }
      }
#pragma unroll
      for (int ni = 0; ni < 4; ++ni) {
        float x0 = xs[cc][jj[ni][0]];
        float x1 = xs[cc][jj[ni][1]];
        float x2 = xs[cc][jj[ni][2]];
#pragma unroll
        for (int u = 0; u < UO; ++u)
          acc[u][ni] += wvv[0][u] * x0 + wvv[1][u] * x1 + wvv[2][u] * x2;
      }
    }
  }
  const unsigned short* bi16 = (const unsigned short*)biasv;
  const float* bi32 = (const float*)biasv;
#pragma unroll
  for (int u = 0; u < UO; ++u) {
    int o = o0 + ty * UO + u;
    float bv = F ? bi32[o] : b2f(bi16[o]);
    unsigned short st[4];
#pragma unroll
    for (int ni = 0; ni < 4; ++ni) {
      float v = (np[ni] == 0) ? 0.f : (acc[u][ni] + bv);
      st[ni] = f2b(v);
    }
    ushort4 pack; pack.x = st[0]; pack.y = st[1]; pack.z = st[2]; pack.w = st[3];
    *(ushort4*)(out + (b * COUT + o) * 256 + n0 + tx * 4) = pack;
  }
}

// ---------- W pre-transpose: Wt[o][K''] = w[o][c][k], K'' = (c/32)*96 + k*32 + c%32 ----------
__global__ __launch_bounds__(256) void wt_transpose(
    const void* __restrict__ wv, unsigned short* __restrict__ Wt,
    int CIN, int COUT, const int* __restrict__ flags)
{
  const int K = CIN * 3;
  const int total = COUT * K;
  int gid = blockIdx.x * 256 + threadIdx.x;
  if (gid >= total) return;
  const int F = flags[0];
  int o = gid / K;
  int kp = gid - o * K;
  int cc0 = kp / 96;
  int rem = kp - cc0 * 96;
  int k = rem >> 5, ci = rem & 31;
  int c = cc0 * 32 + ci;
  int src = (o * CIN + c) * 3 + k;
  unsigned short v = F ? f2b(((const float*)wv)[src]) : ((const unsigned short*)wv)[src];
  Wt[gid] = v;
}

// ---------- MFMA tree conv: xT [b][256][CIN] -> raw_T [b][256][COUT] ----------
// v4: 512-thread block covers 128 o x ALL 256 n (8 waves of 64x64).
// One barrier-pair per 32-channel chunk (48 MFMAs/wave/phase), reg-staged
// 2-phase pipeline, bijective XCD swizzle (all blocks of a batch share raw%8).
// Staging: x 2 threads/row (2 uint4 each), W 4 threads/row (3 uint4 each).
template<int CIN, int COUT>
__global__ __launch_bounds__(512, 4) void tree_conv_mfma(
    const unsigned short* __restrict__ xT,
    const void* __restrict__ idxv,
    const unsigned short* __restrict__ Wt,   // (COUT, 3*CIN) reordered bf16
    const void* __restrict__ biasv,
    unsigned short* __restrict__ outT,
    const int* __restrict__ flags)
{
  constexpr int K = CIN * 3;
  constexpr int XS = 40;   // xT row stride (shorts): 32 data + 8 pad, 16B-aligned
  constexpr int WS = 104;  // W row stride (shorts): 96 data + 8 pad, 16B-aligned
  __shared__ unsigned short xTl[256 * XS];   // 20.0 KB
  __shared__ unsigned short Wl[128 * WS];    // 26.0 KB
  const int tid = threadIdx.x;
  const int wave = tid >> 6, lane = tid & 63, quad = lane >> 4, l15 = lane & 15;

  // bijective XCD swizzle: all BPB blocks of a batch share raw%8
  const int BPB = gridDim.y;  // 1, 2, or 4 (gridDim.x == 1)
  const unsigned raw = blockIdx.y + gridDim.y * blockIdx.z;
  const int r8 = (int)(raw & 7u);
  const unsigned m9 = raw >> 3;
  const int b = r8 * 32 + (int)(m9 / (unsigned)BPB);
  const int u = (int)(m9 % (unsigned)BPB);
  const int o_blk = u * 128;

  const int o_half = (wave >> 2) * 64;      // 2 o-halves
  const int n_sub = (wave & 3) * 64;        // 4 n-quarters
  const int F = flags[0], G = flags[1];

  int jr[4][3];
  int ng[4];
  {
    const int step = G ? 2 : 1;
    const int* idxb = (const int*)idxv + (size_t)b * 765 * step;
#pragma unroll
    for (int t = 0; t < 4; ++t) {
      int n = n_sub + t * 16 + l15;
      ng[t] = n;
      int mm = n - 1;
#pragma unroll
      for (int k = 0; k < 3; ++k) jr[t][k] = (mm >= 0) ? idxb[(3 * mm + k) * step] : 0;
    }
  }

  f32x4 acc[4][4];
#pragma unroll
  for (int a = 0; a < 4; ++a)
#pragma unroll
    for (int c = 0; c < 4; ++c) acc[a][c] = (f32x4){0.f, 0.f, 0.f, 0.f};

  // per-thread staging sources
  const int xrow = tid >> 1, xcol = (tid & 1) * 16;      // 2 threads per x row
  const unsigned short* xsrc = xT + ((size_t)b * 256 + xrow) * CIN + xcol;   // + c0
  const int wo = tid >> 2, wq = tid & 3;                 // 4 threads per W row
  const unsigned short* wsrc = Wt + (size_t)(o_blk + wo) * K + wq * 24;      // + c0*3

  uint4 xr0, xr1, wr0, wr1, wr2;
  {  // prologue: load chunk c0 = 0
    xr0 = *(const uint4*)(xsrc);
    xr1 = *(const uint4*)(xsrc + 8);
    wr0 = *(const uint4*)(wsrc);
    wr1 = *(const uint4*)(wsrc + 8);
    wr2 = *(const uint4*)(wsrc + 16);
  }

  for (int c0 = 0; c0 < CIN; c0 += 32) {
    __syncthreads();  // previous phase's LDS consumers done
    // commit staged regs to LDS (vmcnt wait for their loads lands here)
    *(uint4*)&xTl[xrow * XS + xcol + 0] = xr0;
    *(uint4*)&xTl[xrow * XS + xcol + 8] = xr1;
    {
      unsigned short* d = &Wl[wo * WS + wq * 24];
      *(uint4*)(d + 0)  = wr0;
      *(uint4*)(d + 8)  = wr1;
      *(uint4*)(d + 16) = wr2;
    }
    __syncthreads();  // LDS ready
    if (c0 + 32 < CIN) {  // issue next chunk's loads; latency hides under MFMAs
      const unsigned short* s = xsrc + c0 + 32;
      xr0 = *(const uint4*)(s);
      xr1 = *(const uint4*)(s + 8);
      const unsigned short* w = wsrc + (size_t)(c0 + 32) * 3;
      wr0 = *(const uint4*)(w);
      wr1 = *(const uint4*)(w + 8);
      wr2 = *(const uint4*)(w + 16);
    }
#pragma unroll
    for (int k = 0; k < 3; ++k) {
      bf16x8 af[4], bfr[4];
#pragma unroll
      for (int t = 0; t < 4; ++t)
        af[t] = *(const bf16x8*)&Wl[(o_half + t * 16 + l15) * WS + k * 32 + quad * 8];
#pragma unroll
      for (int t = 0; t < 4; ++t)
        bfr[t] = *(const bf16x8*)&xTl[jr[t][k] * XS + quad * 8];
#pragma unroll
      for (int to = 0; to < 4; ++to)
#pragma unroll
        for (int tn = 0; tn < 4; ++tn)
          acc[to][tn] = __builtin_amdgcn_mfma_f32_16x16x32_bf16(
              af[to], bfr[tn], acc[to][tn], 0, 0, 0);
    }
  }

  const unsigned short* bi16 = (const unsigned short*)biasv;
  const float* bi32 = (const float*)biasv;
#pragma unroll
  for (int to = 0; to < 4; ++to) {
    int og = o_blk + o_half + to * 16 + quad * 4;
    float b4[4];
#pragma unroll
    for (int r = 0; r < 4; ++r) b4[r] = F ? bi32[og + r] : b2f(bi16[og + r]);
#pragma unroll
    for (int tn = 0; tn < 4; ++tn) {
      int n = ng[tn];
      ushort4 st;
      if (n == 0) {
        st.x = 0; st.y = 0; st.z = 0; st.w = 0;
      } else {
        st.x = f2b(acc[to][tn][0] + b4[0]);
        st.y = f2b(acc[to][tn][1] + b4[1]);
        st.z = f2b(acc[to][tn][2] + b4[2]);
        st.w = f2b(acc[to][tn][3] + b4[3]);
      }
      *(ushort4*)(outT + ((size_t)b * 256 + n) * COUT + og) = st;
    }
  }
}

// ---------- partial stats: grid (NS, B), each block reduces a slice of batch b ----------
__global__ __launch_bounds__(256) void stats_part(
    const unsigned short* __restrict__ raw, int C, float* __restrict__ partials)
{
  const int tid = threadIdx.x;
  const int sidx = blockIdx.x, b = blockIdx.y;
  const int NS = gridDim.x;
  const int nv = C * 32;           // uint4 vectors (8 bf16) per batch
  const int per = nv / NS;         // all launch configs keep this divisible
  const uint4* pv = (const uint4*)(raw + (size_t)b * C * 256) + (size_t)sidx * per;
  float s = 0.f, s2 = 0.f;
  for (int i = tid; i < per; i += 256) {
    uint4 v = pv[i];
    unsigned int ww[4] = {v.x, v.y, v.z, v.w};
#pragma unroll
    for (int q = 0; q < 4; ++q) {
      float f0 = b2f(ww[q] & 0xffffu), f1 = b2f(ww[q] >> 16);
      s += f0 + f1; s2 += f0 * f0 + f1 * f1;
    }
  }
  __shared__ float rs[256], rs2[256];
  rs[tid] = s; rs2[tid] = s2;
  __syncthreads();
  for (int off = 128; off > 0; off >>= 1) {
    if (tid < off) { rs[tid] += rs[tid + off]; rs2[tid] += rs2[tid + off]; }
    __syncthreads();
  }
  if (tid == 0) {
    partials[2 * (b * NS + sidx) + 0] = rs[0];
    partials[2 * (b * NS + sidx) + 1] = rs2[0];
  }
}

// ---------- finalize: one block, thread t = batch t -> stats[b] = {mean, inv} ----------
__global__ __launch_bounds__(256) void stats_fin(
    const float* __restrict__ partials, int C, int NS, float* __restrict__ stats)
{
  const int b = threadIdx.x;
  float s = 0.f, s2 = 0.f;
  for (int i = 0; i < NS; ++i) {
    s += partials[2 * (b * NS + i) + 0];
    s2 += partials[2 * (b * NS + i) + 1];
  }
  const float M = (float)(C * 256);
  float mean = s / M;
  float varv = (s2 - s * s / M) / (M - 1.f);
  varv = fmaxf(varv, 0.f);
  stats[2 * b] = mean;
  stats[2 * b + 1] = 1.f / (sqrtf(varv) + 1e-5f);
}

// ---------- apply norm (+mish), pass-through layout, grid (NS2, B) ----------
__global__ __launch_bounds__(256) void apply_norm(
    const unsigned short* __restrict__ raw, unsigned short* __restrict__ out,
    int C, int act, const float* __restrict__ stats)
{
  const int tid = threadIdx.x;
  const int b = blockIdx.y;
  const int nv = C * 32;  // uint4 vectors per batch
  const float mean = stats[2 * b], inv = stats[2 * b + 1];
  const uint4* pv = (const uint4*)(raw + (size_t)b * C * 256);
  uint4* ov = (uint4*)(out + (size_t)b * C * 256);
  const int stride = gridDim.x * 256;
  for (int i = blockIdx.x * 256 + tid; i < nv; i += stride) {
    uint4 v = pv[i];
    unsigned int ww[4] = {v.x, v.y, v.z, v.w};
    unsigned int rr[4];
#pragma unroll
    for (int q = 0; q < 4; ++q) {
      float f0 = (b2f(ww[q] & 0xffffu) - mean) * inv;
      float f1 = (b2f(ww[q] >> 16) - mean) * inv;
      if (act) { f0 = mish_f(f0); f1 = mish_f(f1); }
      rr[q] = (unsigned)f2b(f0) | ((unsigned)f2b(f1) << 16);
    }
    uint4 r; r.x = rr[0]; r.y = rr[1]; r.z = rr[2]; r.w = rr[3];
    ov[i] = r;
  }
}

// ---------- apply norm (+mish) with 64x64 tile transpose: in[b][R][S] -> out[b][S][R] ----------
__global__ __launch_bounds__(256) void apply_t(
    const unsigned short* __restrict__ in, void* __restrict__ outv,
    int R, int S, int act, int finalw,
    const float* __restrict__ stats, const int* __restrict__ flags)
{
  __shared__ unsigned short tile[64 * 72];  // stride 72 shorts = 144B (16B-aligned)
  const int tid = threadIdx.x;
  const int b = blockIdx.z;
  const int S0 = blockIdx.x * 64, R0 = blockIdx.y * 64;
  const float mean = stats[2 * b], inv = stats[2 * b + 1];
  {
    int r = tid >> 2, c4 = (tid & 3) * 16;
    const unsigned short* src = in + ((size_t)b * R + R0 + r) * S + S0 + c4;
    uint4 u0 = *(const uint4*)src;
    uint4 u1 = *(const uint4*)(src + 8);
    unsigned int ww[8] = {u0.x, u0.y, u0.z, u0.w, u1.x, u1.y, u1.z, u1.w};
    unsigned short tv[16];
#pragma unroll
    for (int q = 0; q < 8; ++q) {
      float f0 = (b2f(ww[q] & 0xffffu) - mean) * inv;
      float f1 = (b2f(ww[q] >> 16) - mean) * inv;
      if (act) { f0 = mish_f(f0); f1 = mish_f(f1); }
      tv[2 * q] = f2b(f0);
      tv[2 * q + 1] = f2b(f1);
    }
    unsigned short* d = &tile[r * 72 + c4];
#pragma unroll
    for (int q = 0; q < 2; ++q) {
      ushort4 p0; p0.x = tv[8*q+0]; p0.y = tv[8*q+1]; p0.z = tv[8*q+2]; p0.w = tv[8*q+3];
      ushort4 p1; p1.x = tv[8*q+4]; p1.y = tv[8*q+5]; p1.z = tv[8*q+6]; p1.w = tv[8*q+7];
      *(ushort4*)(d + 8 * q) = p0;
      *(ushort4*)(d + 8 * q + 4) = p1;
    }
  }
  __syncthreads();
  {
    int s = tid >> 2, rc = (tid & 3) * 16;
    const int wf32 = finalw && flags[0];
    if (wf32) {
      float* of = (float*)outv + ((size_t)b * S + S0 + s) * R + R0 + rc;
#pragma unroll
      for (int q = 0; q < 4; ++q) {
        float4 fv;
        fv.x = b2f(tile[(rc + 4 * q + 0) * 72 + s]);
        fv.y = b2f(tile[(rc + 4 * q + 1) * 72 + s]);
        fv.z = b2f(tile[(rc + 4 * q + 2) * 72 + s]);
        fv.w = b2f(tile[(rc + 4 * q + 3) * 72 + s]);
        *(float4*)(of + 4 * q) = fv;
      }
    } else {
      unsigned short* ob = (unsigned short*)outv + ((size_t)b * S + S0 + s) * R + R0 + rc;
#pragma unroll
      for (int q = 0; q < 4; ++q) {
        ushort4 p;
        p.x = tile[(rc + 4 * q + 0) * 72 + s];
        p.y = tile[(rc + 4 * q + 1) * 72 + s];
        p.z = tile[(rc + 4 * q + 2) * 72 + s];
        p.w = tile[(rc + 4 * q + 3) * 72 + s];
        *(ushort4*)(ob + 4 * q) = p;
      }
    }
  }
}

// ws layout (unchanged, round-3-proven 1KB + 128MiB):
//   [0,1KB)        flags
//   [1KB, +64MiB)  nrm slab (bf16); LAST 2KB doubles as the FINAL stats buffer
//   [+64MiB, +128MiB) raw slab (bf16)
// d_out scratch map (d_out untouched by real output until the final apply_t):
//   [0, 1.5MiB)    Wt transpose scratch
//   [4MiB, +64KB)  stats partials
//   [4MiB+64KB, +2KB) stats2: per-batch {mean,inv} for layers 0..4
extern "C" void kernel_launch(void* const* d_in, const int* in_sizes, int n_in,
                              void* d_out, int out_size, void* d_ws, size_t ws_size,
                              hipStream_t stream) {
  const void* trees = d_in[0];
  const void* indexes = d_in[1];
  const void* W_lin = d_in[2];
  const void* b_lin = d_in[3];
  const void* gam = d_in[4];
  const void* bet = d_in[5];
  const void* mu  = d_in[6];
  const void* var = d_in[7];
  const void* w0 = d_in[8];   const void* bc0 = d_in[9];
  const void* w1 = d_in[10];  const void* bc1 = d_in[11];
  const void* w2 = d_in[12];  const void* bc2 = d_in[13];
  const void* w3 = d_in[14];  const void* bc3 = d_in[15];
  const void* w4 = d_in[16];  const void* bc4 = d_in[17];
  const void* w5 = d_in[18];  const void* bc5 = d_in[19];

  int* flags = (int*)d_ws;
  unsigned short* nrm = (unsigned short*)((char*)d_ws + 1024);
  unsigned short* raw = nrm + 33554432;
  float* statsF = (float*)((char*)d_ws + 1024 + 67108864 - 2048);  // nrm slab tail
  unsigned short* Wt = (unsigned short*)d_out;                     // 1.5 MiB scratch
  float* partials = (float*)((char*)d_out + (4 << 20));            // 64 KB scratch
  float* stats2 = (float*)((char*)d_out + (4 << 20) + 65536);      // 2 KB scratch

  detect_flags<<<1, 256, 0, stream>>>((const unsigned short*)trees,
                                      (const unsigned int*)indexes, flags);

  linear_bn_mish<<<dim3(64, 4), 256, 0, stream>>>(trees, W_lin, b_lin, gam, bet, mu, var,
                                                  nrm, flags);

  // Layer 0 (VALU): 16 -> 32, norm no act
  tree_conv<16, 32, 32><<<dim3(4, 1, 256), 256, 0, stream>>>(nrm, indexes, w0, bc0, raw, flags);
  stats_part<<<dim3(4, 256), 256, 0, stream>>>(raw, 32, partials);
  stats_fin<<<1, 256, 0, stream>>>(partials, 32, 4, stats2);
  apply_norm<<<dim3(4, 256), 256, 0, stream>>>(raw, nrm, 32, 0, stats2);

  // Layer 1 (VALU): 32 -> 64; norm+mish with transpose to [b][n][c]
  tree_conv<32, 64, 64><<<dim3(4, 1, 256), 256, 0, stream>>>(nrm, indexes, w1, bc1, raw, flags);
  stats_part<<<dim3(8, 256), 256, 0, stream>>>(raw, 64, partials);
  stats_fin<<<1, 256, 0, stream>>>(partials, 64, 8, stats2);
  apply_t<<<dim3(4, 1, 256), 256, 0, stream>>>(raw, nrm, 64, 256, 1, 0, stats2, flags);

  // Layer 2 (MFMA): 64 -> 128
  wt_transpose<<<96, 256, 0, stream>>>(w2, Wt, 64, 128, flags);
  tree_conv_mfma<64, 128><<<dim3(1, 1, 256), 512, 0, stream>>>(nrm, indexes, Wt, bc2, raw, flags);
  stats_part<<<dim3(8, 256), 256, 0, stream>>>(raw, 128, partials);
  stats_fin<<<1, 256, 0, stream>>>(partials, 128, 8, stats2);
  apply_norm<<<dim3(8, 256), 256, 0, stream>>>(raw, nrm, 128, 1, stats2);

  // Layer 3 (MFMA): 128 -> 256
  wt_transpose<<<384, 256, 0, stream>>>(w3, Wt, 128, 256, flags);
  tree_conv_mfma<128, 256><<<dim3(1, 2, 256), 512, 0, stream>>>(nrm, indexes, Wt, bc3, raw, flags);
  stats_part<<<dim3(16, 256), 256, 0, stream>>>(raw, 256, partials);
  stats_fin<<<1, 256, 0, stream>>>(partials, 256, 16, stats2);
  apply_norm<<<dim3(8, 256), 256, 0, stream>>>(raw, nrm, 256, 1, stats2);

  // Layer 4 (MFMA): 256 -> 512
  wt_transpose<<<1536, 256, 0, stream>>>(w4, Wt, 256, 512, flags);
  tree_conv_mfma<256, 512><<<dim3(1, 4, 256), 512, 0, stream>>>(nrm, indexes, Wt, bc4, raw, flags);
  stats_part<<<dim3(16, 256), 256, 0, stream>>>(raw, 512, partials);
  stats_fin<<<1, 256, 0, stream>>>(partials, 512, 16, stats2);
  apply_norm<<<dim3(16, 256), 256, 0, stream>>>(raw, nrm, 512, 1, stats2);

  // Layer 5 (MFMA): 512 -> 512; final norm+mish transposes back and writes d_out
  wt_transpose<<<3072, 256, 0, stream>>>(w5, Wt, 512, 512, flags);
  tree_conv_mfma<512, 512><<<dim3(1, 4, 256), 512, 0, stream>>>(nrm, indexes, Wt, bc5, raw, flags);
  stats_part<<<dim3(16, 256), 256, 0, stream>>>(raw, 512, partials);   // partials in d_out: Wt dead
  stats_fin<<<1, 256, 0, stream>>>(partials, 512, 16, statsF);         // statsF in dead nrm tail
  apply_t<<<dim3(8, 4, 256), 256, 0, stream>>>(raw, d_out, 256, 512, 1, 1, statsF, flags);
}

// Round 6
// 975.498 us; speedup vs baseline: 1.0678x; 1.0678x over previous
//
#include <hip/hip_runtime.h>
#include <hip/hip_bf16.h>

typedef __attribute__((ext_vector_type(8))) short bf16x8;
typedef __attribute__((ext_vector_type(4))) float f32x4;

// ---------- helpers ----------
__device__ __forceinline__ float b2f(unsigned int u) {
  union { unsigned int i; float f; } v; v.i = u << 16; return v.f;
}
__device__ __forceinline__ unsigned short f2b(float f) {
  unsigned int x = __float_as_uint(f);
  unsigned int r = (x + 0x7fffu + ((x >> 16) & 1u)) >> 16;  // RNE
  return (unsigned short)r;
}
__device__ __forceinline__ float mish_f(float x) {
  float sp = (x > 20.f) ? x : log1pf(expf(x));
  return x * tanhf(sp);
}

// ---------- dtype detector: flags[0]=inputs are f32, flags[1]=indexes are i64 ----------
__global__ __launch_bounds__(256) void detect_flags(
    const unsigned short* __restrict__ trees_u16,
    const unsigned int* __restrict__ idx_u32, int* __restrict__ flags)
{
  __shared__ int cnt_sane, cnt_nz;
  const int tid = threadIdx.x;
  if (tid == 0) { cnt_sane = 0; cnt_nz = 0; }
  __syncthreads();
  int sane = 0;
  for (int i = tid; i < 2048; i += 256) {
    unsigned short w = trees_u16[i];
    unsigned int e = (w >> 7) & 0xFFu;
    if ((w & 0x7FFFu) == 0 || (e >= 117u && e <= 133u)) sane++;
  }
  atomicAdd(&cnt_sane, sane);
  int nz = 0;
  for (int i = tid; i < 4096; i += 256) {
    if (idx_u32[2 * i + 1] != 0u) nz++;
  }
  atomicAdd(&cnt_nz, nz);
  __syncthreads();
  if (tid == 0) {
    flags[0] = (cnt_sane < 1843) ? 1 : 0;
    flags[1] = (cnt_nz == 0) ? 1 : 0;
  }
}

// ---------- K1: x = mish(bn(trees @ W_lin^T + b_lin)) -> (256,16,256) bf16 ----------
__global__ __launch_bounds__(256) void linear_bn_mish(
    const void* __restrict__ treesv, const void* __restrict__ Wlv,
    const void* __restrict__ blv, const void* __restrict__ gamv,
    const void* __restrict__ betv, const void* __restrict__ muv,
    const void* __restrict__ varv, unsigned short* __restrict__ out,
    const int* __restrict__ flags)
{
  __shared__ float As[16][64];
  __shared__ float Bs[16][64];
  const int F = flags[0];
  const int tid = threadIdx.x;
  const int tx = tid & 15, ty = tid >> 4;
  const int j0 = blockIdx.x * 64, b0 = blockIdx.y * 64;
  const int lr = tid >> 2, lc = (tid & 3) << 2;
  const unsigned short* t16 = (const unsigned short*)treesv;
  const float* t32 = (const float*)treesv;
  const unsigned short* w16 = (const unsigned short*)Wlv;
  const float* w32 = (const float*)Wlv;
  float acc[4][4] = {};
  for (int k0 = 0; k0 < 512; k0 += 16) {
    float a0, a1, a2, a3, q0, q1, q2, q3;
    if (F) {
      float4 ta = *(const float4*)(t32 + (b0 + lr) * 512 + k0 + lc);
      float4 tb = *(const float4*)(w32 + (j0 + lr) * 512 + k0 + lc);
      a0 = ta.x; a1 = ta.y; a2 = ta.z; a3 = ta.w;
      q0 = tb.x; q1 = tb.y; q2 = tb.z; q3 = tb.w;
    } else {
      ushort4 ta = *(const ushort4*)(t16 + (b0 + lr) * 512 + k0 + lc);
      ushort4 tb = *(const ushort4*)(w16 + (j0 + lr) * 512 + k0 + lc);
      a0 = b2f(ta.x); a1 = b2f(ta.y); a2 = b2f(ta.z); a3 = b2f(ta.w);
      q0 = b2f(tb.x); q1 = b2f(tb.y); q2 = b2f(tb.z); q3 = b2f(tb.w);
    }
    __syncthreads();
    As[lc + 0][lr] = a0; As[lc + 1][lr] = a1; As[lc + 2][lr] = a2; As[lc + 3][lr] = a3;
    Bs[lc + 0][lr] = q0; Bs[lc + 1][lr] = q1; Bs[lc + 2][lr] = q2; Bs[lc + 3][lr] = q3;
    __syncthreads();
#pragma unroll
    for (int kk = 0; kk < 16; ++kk) {
      float4 av = *(const float4*)&As[kk][ty * 4];
      float4 bv = *(const float4*)&Bs[kk][tx * 4];
      float a[4] = {av.x, av.y, av.z, av.w};
      float bb[4] = {bv.x, bv.y, bv.z, bv.w};
#pragma unroll
      for (int iy = 0; iy < 4; ++iy)
#pragma unroll
        for (int jx = 0; jx < 4; ++jx) acc[iy][jx] += a[iy] * bb[jx];
    }
  }
  const unsigned short* bl16 = (const unsigned short*)blv;  const float* bl32 = (const float*)blv;
  const unsigned short* g16 = (const unsigned short*)gamv;  const float* g32 = (const float*)gamv;
  const unsigned short* be16 = (const unsigned short*)betv; const float* be32 = (const float*)betv;
  const unsigned short* m16 = (const unsigned short*)muv;   const float* m32 = (const float*)muv;
  const unsigned short* v16 = (const unsigned short*)varv;  const float* v32 = (const float*)varv;
#pragma unroll
  for (int iy = 0; iy < 4; ++iy) {
    int b = b0 + ty * 4 + iy;
    unsigned short st[4];
#pragma unroll
    for (int jx = 0; jx < 4; ++jx) {
      int j = j0 + tx * 4 + jx;
      float bj = F ? bl32[j] : b2f(bl16[j]);
      float gj = F ? g32[j] : b2f(g16[j]);
      float ej = F ? be32[j] : b2f(be16[j]);
      float mj = F ? m32[j] : b2f(m16[j]);
      float vj = F ? v32[j] : b2f(v16[j]);
      float v = acc[iy][jx] + bj;
      v = (v - mj) * rsqrtf(vj + 1e-5f) * gj + ej;
      v = mish_f(v);
      st[jx] = f2b(v);
    }
    ushort4 pack; pack.x = st[0]; pack.y = st[1]; pack.z = st[2]; pack.w = st[3];
    *(ushort4*)(out + b * 4096 + j0 + tx * 4) = pack;
  }
}

// ---------- VALU tree conv (small layers 0,1): x [b][c][n] -> raw [b][o][n] ----------
template<int CIN, int COUT, int TO>
__global__ __launch_bounds__(256) void tree_conv(
    const unsigned short* __restrict__ xin,
    const void* __restrict__ idxv,
    const void* __restrict__ wv,
    const void* __restrict__ biasv,
    unsigned short* __restrict__ out,
    const int* __restrict__ flags)
{
  constexpr int CC = 16;
  constexpr int KC = CC * 3;
  constexpr int UO = TO / 16;
  constexpr int PE = (TO * KC) / 256;
  __shared__ float xs[CC][256];
  __shared__ float wsm[KC][TO];
  const int F = flags[0], G = flags[1];
  const int tid = threadIdx.x;
  const int tx = tid & 15, ty = tid >> 4;
  const int b = blockIdx.z;
  const int o0 = blockIdx.y * TO;
  const int n0 = blockIdx.x * 64;
  const unsigned short* xb = xin + b * CIN * 256;
  const unsigned short* wt16 = (const unsigned short*)wv;
  const float* wt32 = (const float*)wv;
  const int* idx32 = (const int*)idxv;

  int jj[4][3];
  int np[4];
  {
    const int step = G ? 2 : 1;
    const int* idxb = idx32 + b * 765 * step;
#pragma unroll
    for (int ni = 0; ni < 4; ++ni) {
      int n = n0 + tx * 4 + ni;
      np[ni] = n;
      int m = n - 1;
#pragma unroll
      for (int k = 0; k < 3; ++k) jj[ni][k] = (m >= 0) ? idxb[(3 * m + k) * step] : 0;
    }
  }

  float acc[UO][4];
#pragma unroll
  for (int u = 0; u < UO; ++u)
#pragma unroll
    for (int ni = 0; ni < 4; ++ni) acc[u][ni] = 0.f;

  for (int c0 = 0; c0 < CIN; c0 += CC) {
    __syncthreads();
    {
      const uint4* src = (const uint4*)(xb + c0 * 256);
      uint4 v0 = src[tid * 2];
      uint4 v1 = src[tid * 2 + 1];
      unsigned int ww[8] = {v0.x, v0.y, v0.z, v0.w, v1.x, v1.y, v1.z, v1.w};
      float t[16];
#pragma unroll
      for (int q = 0; q < 8; ++q) {
        t[2 * q] = b2f(ww[q] & 0xffffu);
        t[2 * q + 1] = b2f(ww[q] >> 16);
      }
      float* dst = &xs[tid >> 4][(tid & 15) * 16];
#pragma unroll
      for (int q = 0; q < 4; ++q)
        *(float4*)(dst + 4 * q) = make_float4(t[4 * q], t[4 * q + 1], t[4 * q + 2], t[4 * q + 3]);
    }
    if (F) {
#pragma unroll
      for (int e = 0; e < PE; ++e) {
        int p = e * 256 + tid;
        int o_rel = p / KC;
        int rem = p - o_rel * KC;
        wsm[rem][o_rel] = wt32[(o0 + o_rel) * CIN * 3 + c0 * 3 + rem];
      }
    } else {
#pragma unroll
      for (int e = 0; e < PE; ++e) {
        int p = e * 256 + tid;
        int o_rel = p / KC;
        int rem = p - o_rel * KC;
        wsm[rem][o_rel] = b2f(wt16[(o0 + o_rel) * CIN * 3 + c0 * 3 + rem]);
      }
    }
    __syncthreads();
#pragma unroll
    for (int cc = 0; cc < CC; ++cc) {
      float wvv[3][UO];
#pragma unroll
      for (int k = 0; k < 3; ++k) {
        if constexpr (UO == 4) {
          float4 f = *(const float4*)&wsm[cc * 3 + k][ty * 4];
          wvv[k][0] = f.x; wvv[k][1] = f.y; wvv[k][2] = f.z; wvv[k][3] = f.w;
        } else {
          float2 f = *(const float2*)&wsm[cc * 3 + k][ty * 2];
          wvv[k][0] = f.x; wvv[k][1] = f.y;
        }
      }
#pragma unroll
      for (int ni = 0; ni < 4; ++ni) {
        float x0 = xs[cc][jj[ni][0]];
        float x1 = xs[cc][jj[ni][1]];
        float x2 = xs[cc][jj[ni][2]];
#pragma unroll
        for (int u = 0; u < UO; ++u)
          acc[u][ni] += wvv[0][u] * x0 + wvv[1][u] * x1 + wvv[2][u] * x2;
      }
    }
  }
  const unsigned short* bi16 = (const unsigned short*)biasv;
  const float* bi32 = (const float*)biasv;
#pragma unroll
  for (int u = 0; u < UO; ++u) {
    int o = o0 + ty * UO + u;
    float bv = F ? bi32[o] : b2f(bi16[o]);
    unsigned short st[4];
#pragma unroll
    for (int ni = 0; ni < 4; ++ni) {
      float v = (np[ni] == 0) ? 0.f : (acc[u][ni] + bv);
      st[ni] = f2b(v);
    }
    ushort4 pack; pack.x = st[0]; pack.y = st[1]; pack.z = st[2]; pack.w = st[3];
    *(ushort4*)(out + (b * COUT + o) * 256 + n0 + tx * 4) = pack;
  }
}

// ---------- W pre-transpose: Wt[o][K''] = w[o][c][k], K'' = (c/32)*96 + k*32 + c%32 ----------
__global__ __launch_bounds__(256) void wt_transpose(
    const void* __restrict__ wv, unsigned short* __restrict__ Wt,
    int CIN, int COUT, const int* __restrict__ flags)
{
  const int K = CIN * 3;
  const int total = COUT * K;
  int gid = blockIdx.x * 256 + threadIdx.x;
  if (gid >= total) return;
  const int F = flags[0];
  int o = gid / K;
  int kp = gid - o * K;
  int cc0 = kp / 96;
  int rem = kp - cc0 * 96;
  int k = rem >> 5, ci = rem & 31;
  int c = cc0 * 32 + ci;
  int src = (o * CIN + c) * 3 + k;
  unsigned short v = F ? f2b(((const float*)wv)[src]) : ((const unsigned short*)wv)[src];
  Wt[gid] = v;
}

// ---------- MFMA tree conv: xT [b][256][CIN] -> raw_T [b][256][COUT] ----------
// Block: 128 o x 128 n, 4 waves (2x2), each wave 64x64 via 4x4 mfma_16x16x32 tiles.
// v5 = v3 (983us proven) + xTl chunk-XOR swizzle: the 16B chunk slot within each
// row is XOR'd by (row>>3)&3 on BOTH the staging write and the bfr gather read.
// With XS=40 (20 dwords), rows collide in banks iff equal mod 8; tree gather rows
// cluster mod 8 -> measured 25.2M conflict cycles. After XOR, collisions need
// equality mod 32 (staging writes become exact 2-way = free).
template<int CIN, int COUT>
__global__ __launch_bounds__(256) void tree_conv_mfma(
    const unsigned short* __restrict__ xT,
    const void* __restrict__ idxv,
    const unsigned short* __restrict__ Wt,   // (COUT, 3*CIN) reordered bf16
    const void* __restrict__ biasv,
    unsigned short* __restrict__ outT,
    const int* __restrict__ flags)
{
  constexpr int K = CIN * 3;
  constexpr int XS = 40;   // xT row stride (shorts): 32 data + 8 pad, 16B-aligned
  constexpr int WS = 104;  // W row stride (shorts): 96 data + 8 pad, 16B-aligned
  __shared__ unsigned short xTl[256 * XS];   // 20.0 KB
  __shared__ unsigned short Wl[128 * WS];    // 26.0 KB
  const int tid = threadIdx.x;
  const int wave = tid >> 6, lane = tid & 63, quad = lane >> 4, l15 = lane & 15;

  // bijective XCD swizzle: all BPB blocks of a batch share raw%8
  const int BPB = gridDim.x * gridDim.y;  // 2, 4, or 8
  const unsigned raw = blockIdx.x + gridDim.x * (blockIdx.y + gridDim.y * blockIdx.z);
  const int r8 = (int)(raw & 7u);
  const unsigned m9 = raw >> 3;
  const int b = r8 * 32 + (int)(m9 / (unsigned)BPB);
  const int u = (int)(m9 % (unsigned)BPB);
  const int n_blk = (u & 1) * 128, o_blk = (u >> 1) * 128;

  const int o_half = (wave >> 1) * 64, n_half = (wave & 1) * 64;
  const int F = flags[0], G = flags[1];

  // gather offsets into swizzled xTl, loop-invariant (precomputed)
  int jroff[4][3];
  int ng[4];
  {
    const int step = G ? 2 : 1;
    const int* idxb = (const int*)idxv + (size_t)b * 765 * step;
#pragma unroll
    for (int t = 0; t < 4; ++t) {
      int n = n_blk + n_half + t * 16 + l15;
      ng[t] = n;
      int mm = n - 1;
#pragma unroll
      for (int k = 0; k < 3; ++k) {
        int j = (mm >= 0) ? idxb[(3 * mm + k) * step] : 0;
        jroff[t][k] = j * XS + ((quad ^ ((j >> 3) & 3)) << 3);
      }
    }
  }

  f32x4 acc[4][4];
#pragma unroll
  for (int a = 0; a < 4; ++a)
#pragma unroll
    for (int c = 0; c < 4; ++c) acc[a][c] = (f32x4){0.f, 0.f, 0.f, 0.f};

  // per-thread staging sources
  const unsigned short* xsrc = xT + ((size_t)b * 256 + tid) * CIN;        // + c0
  const int wo = tid >> 1, wpart = tid & 1;
  const unsigned short* wsrc = Wt + (size_t)(o_blk + wo) * K + wpart * 48;  // + c0*3
  const int xsw = (tid >> 3) & 3;  // staging row = tid -> chunk XOR

  uint4 xr0, xr1, xr2, xr3, wr0, wr1, wr2, wr3, wr4, wr5;
  {  // prologue: load chunk c0 = 0
    const unsigned short* s = xsrc;
    xr0 = *(const uint4*)(s);      xr1 = *(const uint4*)(s + 8);
    xr2 = *(const uint4*)(s + 16); xr3 = *(const uint4*)(s + 24);
    const unsigned short* w = wsrc;
    wr0 = *(const uint4*)(w);      wr1 = *(const uint4*)(w + 8);
    wr2 = *(const uint4*)(w + 16); wr3 = *(const uint4*)(w + 24);
    wr4 = *(const uint4*)(w + 32); wr5 = *(const uint4*)(w + 40);
  }

  for (int c0 = 0; c0 < CIN; c0 += 32) {
    __syncthreads();  // previous phase's LDS consumers done
    // commit staged regs to LDS, chunk slots XOR-swizzled by row bits
    *(uint4*)&xTl[tid * XS + ((0 ^ xsw) << 3)] = xr0;
    *(uint4*)&xTl[tid * XS + ((1 ^ xsw) << 3)] = xr1;
    *(uint4*)&xTl[tid * XS + ((2 ^ xsw) << 3)] = xr2;
    *(uint4*)&xTl[tid * XS + ((3 ^ xsw) << 3)] = xr3;
    {
      unsigned short* d = &Wl[wo * WS + wpart * 48];
      *(uint4*)(d + 0)  = wr0;
      *(uint4*)(d + 8)  = wr1;
      *(uint4*)(d + 16) = wr2;
      *(uint4*)(d + 24) = wr3;
      *(uint4*)(d + 32) = wr4;
      *(uint4*)(d + 40) = wr5;
    }
    __syncthreads();  // LDS ready
    if (c0 + 32 < CIN) {  // issue next chunk's loads; latency hides under MFMAs
      const unsigned short* s = xsrc + c0 + 32;
      xr0 = *(const uint4*)(s);      xr1 = *(const uint4*)(s + 8);
      xr2 = *(const uint4*)(s + 16); xr3 = *(const uint4*)(s + 24);
      const unsigned short* w = wsrc + (size_t)(c0 + 32) * 3;
      wr0 = *(const uint4*)(w);      wr1 = *(const uint4*)(w + 8);
      wr2 = *(const uint4*)(w + 16); wr3 = *(const uint4*)(w + 24);
      wr4 = *(const uint4*)(w + 32); wr5 = *(const uint4*)(w + 40);
    }
#pragma unroll
    for (int k = 0; k < 3; ++k) {
      bf16x8 af[4], bfr[4];
#pragma unroll
      for (int t = 0; t < 4; ++t)
        af[t] = *(const bf16x8*)&Wl[(o_half + t * 16 + l15) * WS + k * 32 + quad * 8];
#pragma unroll
      for (int t = 0; t < 4; ++t)
        bfr[t] = *(const bf16x8*)&xTl[jroff[t][k]];
#pragma unroll
      for (int to = 0; to < 4; ++to)
#pragma unroll
        for (int tn = 0; tn < 4; ++tn)
          acc[to][tn] = __builtin_amdgcn_mfma_f32_16x16x32_bf16(
              af[to], bfr[tn], acc[to][tn], 0, 0, 0);
    }
  }

  const unsigned short* bi16 = (const unsigned short*)biasv;
  const float* bi32 = (const float*)biasv;
#pragma unroll
  for (int to = 0; to < 4; ++to) {
    int og = o_blk + o_half + to * 16 + quad * 4;
    float b4[4];
#pragma unroll
    for (int r = 0; r < 4; ++r) b4[r] = F ? bi32[og + r] : b2f(bi16[og + r]);
#pragma unroll
    for (int tn = 0; tn < 4; ++tn) {
      int n = ng[tn];
      ushort4 st;
      if (n == 0) {
        st.x = 0; st.y = 0; st.z = 0; st.w = 0;
      } else {
        st.x = f2b(acc[to][tn][0] + b4[0]);
        st.y = f2b(acc[to][tn][1] + b4[1]);
        st.z = f2b(acc[to][tn][2] + b4[2]);
        st.w = f2b(acc[to][tn][3] + b4[3]);
      }
      *(ushort4*)(outT + ((size_t)b * 256 + n) * COUT + og) = st;
    }
  }
}

// ---------- partial stats: grid (NS, B), each block reduces a slice of batch b ----------
__global__ __launch_bounds__(256) void stats_part(
    const unsigned short* __restrict__ raw, int C, float* __restrict__ partials)
{
  const int tid = threadIdx.x;
  const int sidx = blockIdx.x, b = blockIdx.y;
  const int NS = gridDim.x;
  const int nv = C * 32;           // uint4 vectors (8 bf16) per batch
  const int per = nv / NS;         // all launch configs keep this divisible
  const uint4* pv = (const uint4*)(raw + (size_t)b * C * 256) + (size_t)sidx * per;
  float s = 0.f, s2 = 0.f;
  for (int i = tid; i < per; i += 256) {
    uint4 v = pv[i];
    unsigned int ww[4] = {v.x, v.y, v.z, v.w};
#pragma unroll
    for (int q = 0; q < 4; ++q) {
      float f0 = b2f(ww[q] & 0xffffu), f1 = b2f(ww[q] >> 16);
      s += f0 + f1; s2 += f0 * f0 + f1 * f1;
    }
  }
  __shared__ float rs[256], rs2[256];
  rs[tid] = s; rs2[tid] = s2;
  __syncthreads();
  for (int off = 128; off > 0; off >>= 1) {
    if (tid < off) { rs[tid] += rs[tid + off]; rs2[tid] += rs2[tid + off]; }
    __syncthreads();
  }
  if (tid == 0) {
    partials[2 * (b * NS + sidx) + 0] = rs[0];
    partials[2 * (b * NS + sidx) + 1] = rs2[0];
  }
}

// ---------- finalize: one block, thread t = batch t -> stats[b] = {mean, inv} ----------
__global__ __launch_bounds__(256) void stats_fin(
    const float* __restrict__ partials, int C, int NS, float* __restrict__ stats)
{
  const int b = threadIdx.x;
  float s = 0.f, s2 = 0.f;
  for (int i = 0; i < NS; ++i) {
    s += partials[2 * (b * NS + i) + 0];
    s2 += partials[2 * (b * NS + i) + 1];
  }
  const float M = (float)(C * 256);
  float mean = s / M;
  float varv = (s2 - s * s / M) / (M - 1.f);
  varv = fmaxf(varv, 0.f);
  stats[2 * b] = mean;
  stats[2 * b + 1] = 1.f / (sqrtf(varv) + 1e-5f);
}

// ---------- apply norm (+mish), pass-through layout, grid (NS2, B) ----------
__global__ __launch_bounds__(256) void apply_norm(
    const unsigned short* __restrict__ raw, unsigned short* __restrict__ out,
    int C, int act, const float* __restrict__ stats)
{
  const int tid = threadIdx.x;
  const int b = blockIdx.y;
  const int nv = C * 32;  // uint4 vectors per batch
  const float mean = stats[2 * b], inv = stats[2 * b + 1];
  const uint4* pv = (const uint4*)(raw + (size_t)b * C * 256);
  uint4* ov = (uint4*)(out + (size_t)b * C * 256);
  const int stride = gridDim.x * 256;
  for (int i = blockIdx.x * 256 + tid; i < nv; i += stride) {
    uint4 v = pv[i];
    unsigned int ww[4] = {v.x, v.y, v.z, v.w};
    unsigned int rr[4];
#pragma unroll
    for (int q = 0; q < 4; ++q) {
      float f0 = (b2f(ww[q] & 0xffffu) - mean) * inv;
      float f1 = (b2f(ww[q] >> 16) - mean) * inv;
      if (act) { f0 = mish_f(f0); f1 = mish_f(f1); }
      rr[q] = (unsigned)f2b(f0) | ((unsigned)f2b(f1) << 16);
    }
    uint4 r; r.x = rr[0]; r.y = rr[1]; r.z = rr[2]; r.w = rr[3];
    ov[i] = r;
  }
}

// ---------- apply norm (+mish) with 64x64 tile transpose: in[b][R][S] -> out[b][S][R] ----------
__global__ __launch_bounds__(256) void apply_t(
    const unsigned short* __restrict__ in, void* __restrict__ outv,
    int R, int S, int act, int finalw,
    const float* __restrict__ stats, const int* __restrict__ flags)
{
  __shared__ unsigned short tile[64 * 72];  // stride 72 shorts = 144B (16B-aligned)
  const int tid = threadIdx.x;
  const int b = blockIdx.z;
  const int S0 = blockIdx.x * 64, R0 = blockIdx.y * 64;
  const float mean = stats[2 * b], inv = stats[2 * b + 1];
  {
    int r = tid >> 2, c4 = (tid & 3) * 16;
    const unsigned short* src = in + ((size_t)b * R + R0 + r) * S + S0 + c4;
    uint4 u0 = *(const uint4*)src;
    uint4 u1 = *(const uint4*)(src + 8);
    unsigned int ww[8] = {u0.x, u0.y, u0.z, u0.w, u1.x, u1.y, u1.z, u1.w};
    unsigned short tv[16];
#pragma unroll
    for (int q = 0; q < 8; ++q) {
      float f0 = (b2f(ww[q] & 0xffffu) - mean) * inv;
      float f1 = (b2f(ww[q] >> 16) - mean) * inv;
      if (act) { f0 = mish_f(f0); f1 = mish_f(f1); }
      tv[2 * q] = f2b(f0);
      tv[2 * q + 1] = f2b(f1);
    }
    unsigned short* d = &tile[r * 72 + c4];
#pragma unroll
    for (int q = 0; q < 2; ++q) {
      ushort4 p0; p0.x = tv[8*q+0]; p0.y = tv[8*q+1]; p0.z = tv[8*q+2]; p0.w = tv[8*q+3];
      ushort4 p1; p1.x = tv[8*q+4]; p1.y = tv[8*q+5]; p1.z = tv[8*q+6]; p1.w = tv[8*q+7];
      *(ushort4*)(d + 8 * q) = p0;
      *(ushort4*)(d + 8 * q + 4) = p1;
    }
  }
  __syncthreads();
  {
    int s = tid >> 2, rc = (tid & 3) * 16;
    const int wf32 = finalw && flags[0];
    if (wf32) {
      float* of = (float*)outv + ((size_t)b * S + S0 + s) * R + R0 + rc;
#pragma unroll
      for (int q = 0; q < 4; ++q) {
        float4 fv;
        fv.x = b2f(tile[(rc + 4 * q + 0) * 72 + s]);
        fv.y = b2f(tile[(rc + 4 * q + 1) * 72 + s]);
        fv.z = b2f(tile[(rc + 4 * q + 2) * 72 + s]);
        fv.w = b2f(tile[(rc + 4 * q + 3) * 72 + s]);
        *(float4*)(of + 4 * q) = fv;
      }
    } else {
      unsigned short* ob = (unsigned short*)outv + ((size_t)b * S + S0 + s) * R + R0 + rc;
#pragma unroll
      for (int q = 0; q < 4; ++q) {
        ushort4 p;
        p.x = tile[(rc + 4 * q + 0) * 72 + s];
        p.y = tile[(rc + 4 * q + 1) * 72 + s];
        p.z = tile[(rc + 4 * q + 2) * 72 + s];
        p.w = tile[(rc + 4 * q + 3) * 72 + s];
        *(ushort4*)(ob + 4 * q) = p;
      }
    }
  }
}

// ws layout (unchanged, round-3-proven 1KB + 128MiB):
//   [0,1KB)        flags
//   [1KB, +64MiB)  nrm slab (bf16); LAST 2KB doubles as the FINAL stats buffer
//   [+64MiB, +128MiB) raw slab (bf16)
// d_out scratch map (d_out untouched by real output until the final apply_t):
//   [0, 1.5MiB)    Wt transpose scratch
//   [4MiB, +64KB)  stats partials
//   [4MiB+64KB, +2KB) stats2: per-batch {mean,inv} for layers 0..4
extern "C" void kernel_launch(void* const* d_in, const int* in_sizes, int n_in,
                              void* d_out, int out_size, void* d_ws, size_t ws_size,
                              hipStream_t stream) {
  const void* trees = d_in[0];
  const void* indexes = d_in[1];
  const void* W_lin = d_in[2];
  const void* b_lin = d_in[3];
  const void* gam = d_in[4];
  const void* bet = d_in[5];
  const void* mu  = d_in[6];
  const void* var = d_in[7];
  const void* w0 = d_in[8];   const void* bc0 = d_in[9];
  const void* w1 = d_in[10];  const void* bc1 = d_in[11];
  const void* w2 = d_in[12];  const void* bc2 = d_in[13];
  const void* w3 = d_in[14];  const void* bc3 = d_in[15];
  const void* w4 = d_in[16];  const void* bc4 = d_in[17];
  const void* w5 = d_in[18];  const void* bc5 = d_in[19];

  int* flags = (int*)d_ws;
  unsigned short* nrm = (unsigned short*)((char*)d_ws + 1024);
  unsigned short* raw = nrm + 33554432;
  float* statsF = (float*)((char*)d_ws + 1024 + 67108864 - 2048);  // nrm slab tail
  unsigned short* Wt = (unsigned short*)d_out;                     // 1.5 MiB scratch
  float* partials = (float*)((char*)d_out + (4 << 20));            // 64 KB scratch
  float* stats2 = (float*)((char*)d_out + (4 << 20) + 65536);      // 2 KB scratch

  detect_flags<<<1, 256, 0, stream>>>((const unsigned short*)trees,
                                      (const unsigned int*)indexes, flags);

  linear_bn_mish<<<dim3(64, 4), 256, 0, stream>>>(trees, W_lin, b_lin, gam, bet, mu, var,
                                                  nrm, flags);

  // Layer 0 (VALU): 16 -> 32, norm no act
  tree_conv<16, 32, 32><<<dim3(4, 1, 256), 256, 0, stream>>>(nrm, indexes, w0, bc0, raw, flags);
  stats_part<<<dim3(4, 256), 256, 0, stream>>>(raw, 32, partials);
  stats_fin<<<1, 256, 0, stream>>>(partials, 32, 4, stats2);
  apply_norm<<<dim3(4, 256), 256, 0, stream>>>(raw, nrm, 32, 0, stats2);

  // Layer 1 (VALU): 32 -> 64; norm+mish with transpose to [b][n][c]
  tree_conv<32, 64, 64><<<dim3(4, 1, 256), 256, 0, stream>>>(nrm, indexes, w1, bc1, raw, flags);
  stats_part<<<dim3(8, 256), 256, 0, stream>>>(raw, 64, partials);
  stats_fin<<<1, 256, 0, stream>>>(partials, 64, 8, stats2);
  apply_t<<<dim3(4, 1, 256), 256, 0, stream>>>(raw, nrm, 64, 256, 1, 0, stats2, flags);

  // Layer 2 (MFMA): 64 -> 128
  wt_transpose<<<96, 256, 0, stream>>>(w2, Wt, 64, 128, flags);
  tree_conv_mfma<64, 128><<<dim3(2, 1, 256), 256, 0, stream>>>(nrm, indexes, Wt, bc2, raw, flags);
  stats_part<<<dim3(8, 256), 256, 0, stream>>>(raw, 128, partials);
  stats_fin<<<1, 256, 0, stream>>>(partials, 128, 8, stats2);
  apply_norm<<<dim3(8, 256), 256, 0, stream>>>(raw, nrm, 128, 1, stats2);

  // Layer 3 (MFMA): 128 -> 256
  wt_transpose<<<384, 256, 0, stream>>>(w3, Wt, 128, 256, flags);
  tree_conv_mfma<128, 256><<<dim3(2, 2, 256), 256, 0, stream>>>(nrm, indexes, Wt, bc3, raw, flags);
  stats_part<<<dim3(16, 256), 256, 0, stream>>>(raw, 256, partials);
  stats_fin<<<1, 256, 0, stream>>>(partials, 256, 16, stats2);
  apply_norm<<<dim3(8, 256), 256, 0, stream>>>(raw, nrm, 256, 1, stats2);

  // Layer 4 (MFMA): 256 -> 512
  wt_transpose<<<1536, 256, 0, stream>>>(w4, Wt, 256, 512, flags);
  tree_conv_mfma<256, 512><<<dim3(2, 4, 256), 256, 0, stream>>>(nrm, indexes, Wt, bc4, raw, flags);
  stats_part<<<dim3(16, 256), 256, 0, stream>>>(raw, 512, partials);
  stats_fin<<<1, 256, 0, stream>>>(partials, 512, 16, stats2);
  apply_norm<<<dim3(16, 256), 256, 0, stream>>>(raw, nrm, 512, 1, stats2);

  // Layer 5 (MFMA): 512 -> 512; final norm+mish transposes back and writes d_out
  wt_transpose<<<3072, 256, 0, stream>>>(w5, Wt, 512, 512, flags);
  tree_conv_mfma<512, 512><<<dim3(2, 4, 256), 256, 0, stream>>>(nrm, indexes, Wt, bc5, raw, flags);
  stats_part<<<dim3(16, 256), 256, 0, stream>>>(raw, 512, partials);   // partials in d_out: Wt dead
  stats_fin<<<1, 256, 0, stream>>>(partials, 512, 16, statsF);         // statsF in dead nrm tail
  apply_t<<<dim3(8, 4, 256), 256, 0, stream>>>(raw, d_out, 256, 512, 1, 1, statsF, flags);
}